// Round 1
// baseline (2329.844 us; speedup 1.0000x reference)
//
#include <hip/hip_runtime.h>

#define TT 4096
#define HD 2048
#define FD 768
#define NE 32
#define TOPK 4
#define NSG 8
#define CAPE 1024

typedef __attribute__((ext_vector_type(8))) short short8;
typedef __attribute__((ext_vector_type(4))) float f32x4;
typedef __attribute__((ext_vector_type(4))) unsigned short us4;

// XOR-swizzled LDS index for [row][64] bf16 tiles: permutes 16B blocks within a row
#define SWZ(r, k) (((r) << 6) + ((k) ^ (((r) & 7) << 3)))

__device__ __forceinline__ unsigned short f2bf(float f) {
  unsigned u = __builtin_bit_cast(unsigned, f);
  u += 0x7FFFu + ((u >> 16) & 1u);
  return (unsigned short)(u >> 16);
}

// ---------------- router: fp32 logits, top-4, softmax, fp32 secondary gate ----------------
__global__ __launch_bounds__(256) void router_kernel(
    const float* __restrict__ rin, const float* __restrict__ w_router,
    const float* __restrict__ w_sgate,
    float* __restrict__ top_logits, int* __restrict__ sel,
    float* __restrict__ rwts, unsigned* __restrict__ sgq) {
  __shared__ float rl[4][HD];
  __shared__ float lg[4][NE];
  __shared__ int selS[4][TOPK];
  const int wid = threadIdx.x >> 6, lane = threadIdx.x & 63;
  const int t = blockIdx.x * 4 + wid;

  const float4* src = (const float4*)(rin + (size_t)t * HD);
  float4* dst = (float4*)rl[wid];
#pragma unroll
  for (int i = 0; i < 8; ++i) dst[lane + 64 * i] = src[lane + 64 * i];
  __syncthreads();

  float acc[NE];
#pragma unroll
  for (int e = 0; e < NE; ++e) acc[e] = 0.f;
  for (int i = 0; i < 32; ++i) {
    int h = lane + 64 * i;
    float rv = rl[wid][h];
    const float4* wr4 = (const float4*)(w_router + (size_t)h * NE);
#pragma unroll
    for (int j = 0; j < 8; ++j) {
      float4 w4 = wr4[j];
      acc[j * 4 + 0] += rv * w4.x;
      acc[j * 4 + 1] += rv * w4.y;
      acc[j * 4 + 2] += rv * w4.z;
      acc[j * 4 + 3] += rv * w4.w;
    }
  }
#pragma unroll
  for (int e = 0; e < NE; ++e) {
    float v = acc[e];
#pragma unroll
    for (int off = 32; off > 0; off >>= 1) v += __shfl_down(v, off);
    if (lane == 0) lg[wid][e] = v;
  }
  if (lane == 0) {
    float val[TOPK];
    int idx[TOPK];
    unsigned used = 0;
#pragma unroll
    for (int k = 0; k < TOPK; ++k) {
      float best = -1e30f;
      int bi = 0;
      for (int e2 = 0; e2 < NE; ++e2) {
        float v = lg[wid][e2];
        if (!((used >> e2) & 1u) && v > best) { best = v; bi = e2; }
      }
      used |= 1u << bi;
      val[k] = best;
      idx[k] = bi;
    }
    float ex[TOPK], sum = 0.f;
#pragma unroll
    for (int k = 0; k < TOPK; ++k) { ex[k] = expf(val[k] - val[0]); sum += ex[k]; }
#pragma unroll
    for (int k = 0; k < TOPK; ++k) {
      top_logits[t * TOPK + k] = val[k];
      sel[t * TOPK + k] = idx[k];
      rwts[t * TOPK + k] = ex[k] / sum;
      selS[wid][k] = idx[k];
    }
  }
  __syncthreads();
  // secondary gate in fp32: z[e,s] = sum_h r[h]*w_sgate[e,h,s]; bit = z>0
  const int sidx = lane >> 3, jj = lane & 7;
#pragma unroll
  for (int k = 0; k < TOPK; ++k) {
    int e = selS[wid][k];
    const float* wsg = w_sgate + (size_t)e * (HD * NSG) + sidx;
    float z = 0.f;
    for (int i = 0; i < HD / 8; ++i) {
      int h = jj + 8 * i;
      z += rl[wid][h] * wsg[(size_t)h * NSG];
    }
    z += __shfl_xor(z, 1);
    z += __shfl_xor(z, 2);
    z += __shfl_xor(z, 4);
    unsigned long long bm = __ballot(z > 0.f);
    if (lane == 0) {
      unsigned b = 0;
#pragma unroll
      for (int s = 0; s < NSG; ++s) b |= (unsigned)((bm >> (s * 8)) & 1ULL) << s;
      sgq[t * TOPK + k] = b;
    }
  }
}

// ---------------- dispatch: ordered compaction per expert (matches lax.top_k stability) -----
__global__ __launch_bounds__(256) void dispatch_kernel(
    const int* __restrict__ sel, const float* __restrict__ rwts,
    const unsigned* __restrict__ sgq,
    int* __restrict__ tok_idx, float* __restrict__ tok_w,
    unsigned* __restrict__ sgbits, int* __restrict__ counts) {
  const int e = blockIdx.x;
  __shared__ int wcnt[4];
  __shared__ int base;
  const int tid = threadIdx.x, lane = tid & 63, wid = tid >> 6;
  if (tid == 0) base = 0;
  __syncthreads();
  for (int t0 = 0; t0 < TT; t0 += 256) {
    int t = t0 + tid;
    int hitk = -1;
#pragma unroll
    for (int k = 0; k < TOPK; ++k)
      if (sel[t * TOPK + k] == e) hitk = k;
    unsigned long long m = __ballot(hitk >= 0);
    if (lane == 0) wcnt[wid] = __popcll(m);
    __syncthreads();
    int off = base;
    for (int w = 0; w < wid; ++w) off += wcnt[w];
    int pos = off + __popcll(m & ((1ULL << lane) - 1ULL));
    if (hitk >= 0 && pos < CAPE) {
      tok_idx[e * CAPE + pos] = t;
      tok_w[e * CAPE + pos] = rwts[t * TOPK + hitk];
      sgbits[e * CAPE + pos] = sgq[t * TOPK + hitk];
    }
    __syncthreads();
    if (tid == 0) base += wcnt[0] + wcnt[1] + wcnt[2] + wcnt[3];
    __syncthreads();
  }
  if (tid == 0) counts[e] = base < CAPE ? base : CAPE;
}

// ---------------- up/gate GEMM + hierarchical gating -> act (bf16) ----------------
__global__ __launch_bounds__(256, 2) void up_gate_kernel(
    const float* __restrict__ x, const float* __restrict__ w_up,
    const float* __restrict__ w_gate, const int* __restrict__ tok_idx,
    const int* __restrict__ counts, const unsigned* __restrict__ sgbits,
    unsigned short* __restrict__ act) {
  const int e = blockIdx.z;
  const int count = counts[e];
  const int m0 = blockIdx.x * 128;
  if (m0 >= count) return;
  const int n0 = blockIdx.y * 128;

  __shared__ __align__(16) unsigned short As[128 * 64];
  __shared__ __align__(16) unsigned short Bu[128 * 64];
  __shared__ __align__(16) unsigned short Bg[128 * 64];

  const int tid = threadIdx.x;
  const int lane = tid & 63, wid = tid >> 6;
  const int wr = wid >> 1, wc = wid & 1;
  const int ecap = e * CAPE;

  // A staging (gather + fp32->bf16): 16 rows x 16 float4-cols per pass, 8 passes
  const int art = tid >> 4, acq = tid & 15;
  const float* aptr[8];
#pragma unroll
  for (int p = 0; p < 8; ++p) {
    int gm = m0 + p * 16 + art;
    int gc = gm < count ? gm : count - 1;
    aptr[p] = x + (size_t)tok_idx[ecap + gc] * HD + acq * 4;
  }
  // B staging (transpose + convert): thread owns column n=tid&127, k-half tid>>7
  const int bn = tid & 127;
  const int bkh = (tid >> 7) << 5;
  const float* upP = w_up + (size_t)e * HD * FD + n0 + bn;
  const float* gaP = w_gate + (size_t)e * HD * FD + n0 + bn;
  unsigned short* BuW = Bu + (bn << 6);
  unsigned short* BgW = Bg + (bn << 6);
  const int bxor = (bn & 7) << 3;

  f32x4 accU[4][4], accG[4][4];
#pragma unroll
  for (int i = 0; i < 4; ++i)
#pragma unroll
    for (int j = 0; j < 4; ++j) { accU[i][j] = (f32x4)0.f; accG[i][j] = (f32x4)0.f; }

  const int fr = lane & 15, fq = lane >> 4;
  const int frx = (fr & 7) << 3;

  for (int kt = 0; kt < HD; kt += 64) {
    __syncthreads();
#pragma unroll
    for (int p = 0; p < 8; ++p) {
      float4 v = *(const float4*)(aptr[p] + kt);
      us4 o = {f2bf(v.x), f2bf(v.y), f2bf(v.z), f2bf(v.w)};
      *(us4*)(As + SWZ(p * 16 + art, acq * 4)) = o;
    }
#pragma unroll
    for (int j2 = 0; j2 < 8; ++j2) {
      int k0 = bkh + j2 * 4;
      const float* u0 = upP + (size_t)(kt + k0) * FD;
      us4 ou = {f2bf(u0[0]), f2bf(u0[FD]), f2bf(u0[2 * FD]), f2bf(u0[3 * FD])};
      *(us4*)(BuW + (k0 ^ bxor)) = ou;
      const float* g0 = gaP + (size_t)(kt + k0) * FD;
      us4 og = {f2bf(g0[0]), f2bf(g0[FD]), f2bf(g0[2 * FD]), f2bf(g0[3 * FD])};
      *(us4*)(BgW + (k0 ^ bxor)) = og;
    }
    __syncthreads();
#pragma unroll
    for (int kk = 0; kk < 64; kk += 32) {
      short8 af[4], bu[4], bg[4];
      const int kphys = (kk + fq * 8) ^ frx;
#pragma unroll
      for (int mi = 0; mi < 4; ++mi)
        af[mi] = *(const short8*)(As + ((wr * 64 + mi * 16 + fr) << 6) + kphys);
#pragma unroll
      for (int ni = 0; ni < 4; ++ni) {
        bu[ni] = *(const short8*)(Bu + ((wc * 64 + ni * 16 + fr) << 6) + kphys);
        bg[ni] = *(const short8*)(Bg + ((wc * 64 + ni * 16 + fr) << 6) + kphys);
      }
#pragma unroll
      for (int mi = 0; mi < 4; ++mi)
#pragma unroll
        for (int ni = 0; ni < 4; ++ni) {
          accU[mi][ni] = __builtin_amdgcn_mfma_f32_16x16x32_bf16(af[mi], bu[ni], accU[mi][ni], 0, 0, 0);
          accG[mi][ni] = __builtin_amdgcn_mfma_f32_16x16x32_bf16(af[mi], bg[ni], accG[mi][ni], 0, 0, 0);
        }
    }
  }
  // epilogue: act = up * relu(gate) * sg[group], store bf16
#pragma unroll
  for (int mi = 0; mi < 4; ++mi) {
#pragma unroll
    for (int q = 0; q < 4; ++q) {
      int grow = m0 + wr * 64 + mi * 16 + fq * 4 + q;
      if (grow < count) {
        unsigned sg = sgbits[ecap + grow];
        unsigned short* arow = act + (size_t)(ecap + grow) * FD + n0 + wc * 64 + fr;
#pragma unroll
        for (int ni = 0; ni < 4; ++ni) {
          int gcol = n0 + wc * 64 + ni * 16 + fr;
          float a = accU[mi][ni][q] * fmaxf(accG[mi][ni][q], 0.f);
          a = ((sg >> (gcol / 96)) & 1u) ? a : 0.f;
          arow[ni * 16] = f2bf(a);
        }
      }
    }
  }
}

// ---------------- down GEMM + weighted scatter-accumulate ----------------
__global__ __launch_bounds__(256, 2) void down_kernel(
    const unsigned short* __restrict__ act, const float* __restrict__ w_down,
    const int* __restrict__ tok_idx, const float* __restrict__ tok_w,
    const int* __restrict__ counts, float* __restrict__ outF) {
  const int e = blockIdx.z;
  const int count = counts[e];
  const int m0 = blockIdx.x * 128;
  if (m0 >= count) return;
  const int n0 = blockIdx.y * 128;

  __shared__ __align__(16) unsigned short As[128 * 64];
  __shared__ __align__(16) unsigned short Bs[128 * 64];

  const int tid = threadIdx.x, lane = tid & 63, wid = tid >> 6;
  const int wr = wid >> 1, wc = wid & 1;
  const int ecap = e * CAPE;

  const int art = tid >> 3, acq = tid & 7;  // 32 rows x 8 uint4 per pass
  const int bn = tid & 127;
  const int bkh = (tid >> 7) << 5;
  const float* dnP = w_down + (size_t)e * FD * HD + n0 + bn;
  unsigned short* BsW = Bs + (bn << 6);
  const int bxor = (bn & 7) << 3;

  f32x4 accD[4][4];
#pragma unroll
  for (int i = 0; i < 4; ++i)
#pragma unroll
    for (int j = 0; j < 4; ++j) accD[i][j] = (f32x4)0.f;

  const int fr = lane & 15, fq = lane >> 4;
  const int frx = (fr & 7) << 3;

  for (int kt = 0; kt < FD; kt += 64) {
    __syncthreads();
#pragma unroll
    for (int p = 0; p < 4; ++p) {
      int row = p * 32 + art;
      uint4 v = *(const uint4*)(act + (size_t)(ecap + m0 + row) * FD + kt + acq * 8);
      *(uint4*)(As + SWZ(row, acq * 8)) = v;
    }
#pragma unroll
    for (int j2 = 0; j2 < 8; ++j2) {
      int k0 = bkh + j2 * 4;
      const float* d0 = dnP + (size_t)(kt + k0) * HD;
      us4 o = {f2bf(d0[0]), f2bf(d0[HD]), f2bf(d0[2 * HD]), f2bf(d0[3 * HD])};
      *(us4*)(BsW + (k0 ^ bxor)) = o;
    }
    __syncthreads();
#pragma unroll
    for (int kk = 0; kk < 64; kk += 32) {
      short8 af[4], bb[4];
      const int kphys = (kk + fq * 8) ^ frx;
#pragma unroll
      for (int mi = 0; mi < 4; ++mi)
        af[mi] = *(const short8*)(As + ((wr * 64 + mi * 16 + fr) << 6) + kphys);
#pragma unroll
      for (int ni = 0; ni < 4; ++ni)
        bb[ni] = *(const short8*)(Bs + ((wc * 64 + ni * 16 + fr) << 6) + kphys);
#pragma unroll
      for (int mi = 0; mi < 4; ++mi)
#pragma unroll
        for (int ni = 0; ni < 4; ++ni)
          accD[mi][ni] = __builtin_amdgcn_mfma_f32_16x16x32_bf16(af[mi], bb[ni], accD[mi][ni], 0, 0, 0);
    }
  }
#pragma unroll
  for (int mi = 0; mi < 4; ++mi) {
#pragma unroll
    for (int q = 0; q < 4; ++q) {
      int grow = m0 + wr * 64 + mi * 16 + fq * 4 + q;
      if (grow < count) {
        float wgt = tok_w[ecap + grow];
        float* dst = outF + (size_t)tok_idx[ecap + grow] * HD + n0 + wc * 64 + fr;
#pragma unroll
        for (int ni = 0; ni < 4; ++ni)
          atomicAdd(dst + ni * 16, accD[mi][ni][q] * wgt);
      }
    }
  }
}

extern "C" void kernel_launch(void* const* d_in, const int* in_sizes, int n_in,
                              void* d_out, int out_size, void* d_ws, size_t ws_size,
                              hipStream_t stream) {
  const float* rin = (const float*)d_in[0];
  const float* x = (const float*)d_in[1];
  const float* w_router = (const float*)d_in[2];
  const float* w_up = (const float*)d_in[3];
  const float* w_gate = (const float*)d_in[4];
  const float* w_down = (const float*)d_in[5];
  const float* w_sg = (const float*)d_in[6];
  float* outF = (float*)d_out;
  float* top_logits = outF + (size_t)TT * HD;

  char* ws = (char*)d_ws;
  int* sel = (int*)(ws + 0);                       // 64 KB
  float* rwts = (float*)(ws + (64 << 10));         // 64 KB
  unsigned* sgq = (unsigned*)(ws + (128 << 10));   // 64 KB
  int* tidx = (int*)(ws + (192 << 10));            // 128 KB
  float* tw = (float*)(ws + (320 << 10));          // 128 KB
  unsigned* sgb = (unsigned*)(ws + (448 << 10));   // 128 KB
  int* counts = (int*)(ws + (576 << 10));          // small
  unsigned short* act = (unsigned short*)(ws + (1 << 20));  // 48 MB bf16 [E][CAP][F]

  hipMemsetAsync(d_out, 0, (size_t)TT * HD * sizeof(float), stream);
  router_kernel<<<TT / 4, 256, 0, stream>>>(rin, w_router, w_sg, top_logits, sel, rwts, sgq);
  dispatch_kernel<<<NE, 256, 0, stream>>>(sel, rwts, sgq, tidx, tw, sgb, counts);
  up_gate_kernel<<<dim3(CAPE / 128, FD / 128, NE), 256, 0, stream>>>(x, w_up, w_gate, tidx, counts, sgb, act);
  down_kernel<<<dim3(CAPE / 128, HD / 128, NE), 256, 0, stream>>>(act, w_down, tidx, tw, counts, outF);
}

// Round 2
// 973.215 us; speedup vs baseline: 2.3940x; 2.3940x over previous
//
#include <hip/hip_runtime.h>

#define TT 4096
#define HD 2048
#define FD 768
#define NE 32
#define TOPK 4
#define NSG 8
#define CAPE 1024

typedef __attribute__((ext_vector_type(8))) short short8;
typedef __attribute__((ext_vector_type(4))) float f32x4;
typedef __attribute__((ext_vector_type(4))) unsigned short us4;
typedef __attribute__((ext_vector_type(8))) unsigned short us8;

// XOR-swizzled LDS index for [row][64] bf16 tiles: permutes 16B blocks within a row
#define SWZ(r, k) (((r) << 6) + ((k) ^ (((r) & 7) << 3)))

__device__ __forceinline__ unsigned short f2bf(float f) {
  unsigned u = __builtin_bit_cast(unsigned, f);
  u += 0x7FFFu + ((u >> 16) & 1u);
  return (unsigned short)(u >> 16);
}

// async global->LDS 16B per lane (dest = wave-uniform base + lane*16)
__device__ __forceinline__ void async16(const void* g, void* l) {
  __builtin_amdgcn_global_load_lds(
      (const __attribute__((address_space(1))) unsigned int*)g,
      (__attribute__((address_space(3))) unsigned int*)l, 16, 0, 0);
}

// ---------------- router: fp32 logits, top-4, softmax, fp32 secondary gate ----------------
__global__ __launch_bounds__(256) void router_kernel(
    const float* __restrict__ rin, const float* __restrict__ w_router,
    const float* __restrict__ w_sgate,
    float* __restrict__ top_logits, int* __restrict__ sel,
    float* __restrict__ rwts, unsigned* __restrict__ sgq) {
  __shared__ float rl[4][HD];
  __shared__ float lg[4][NE];
  __shared__ int selS[4][TOPK];
  const int wid = threadIdx.x >> 6, lane = threadIdx.x & 63;
  const int t = blockIdx.x * 4 + wid;

  const float4* src = (const float4*)(rin + (size_t)t * HD);
  float4* dst = (float4*)rl[wid];
#pragma unroll
  for (int i = 0; i < 8; ++i) dst[lane + 64 * i] = src[lane + 64 * i];
  __syncthreads();

  float acc[NE];
#pragma unroll
  for (int e = 0; e < NE; ++e) acc[e] = 0.f;
  for (int i = 0; i < 32; ++i) {
    int h = lane + 64 * i;
    float rv = rl[wid][h];
    const float4* wr4 = (const float4*)(w_router + (size_t)h * NE);
#pragma unroll
    for (int j = 0; j < 8; ++j) {
      float4 w4 = wr4[j];
      acc[j * 4 + 0] += rv * w4.x;
      acc[j * 4 + 1] += rv * w4.y;
      acc[j * 4 + 2] += rv * w4.z;
      acc[j * 4 + 3] += rv * w4.w;
    }
  }
#pragma unroll
  for (int e = 0; e < NE; ++e) {
    float v = acc[e];
#pragma unroll
    for (int off = 32; off > 0; off >>= 1) v += __shfl_down(v, off);
    if (lane == 0) lg[wid][e] = v;
  }
  if (lane == 0) {
    float val[TOPK];
    int idx[TOPK];
    unsigned used = 0;
#pragma unroll
    for (int k = 0; k < TOPK; ++k) {
      float best = -1e30f;
      int bi = 0;
      for (int e2 = 0; e2 < NE; ++e2) {
        float v = lg[wid][e2];
        if (!((used >> e2) & 1u) && v > best) { best = v; bi = e2; }
      }
      used |= 1u << bi;
      val[k] = best;
      idx[k] = bi;
    }
    float ex[TOPK], sum = 0.f;
#pragma unroll
    for (int k = 0; k < TOPK; ++k) { ex[k] = expf(val[k] - val[0]); sum += ex[k]; }
#pragma unroll
    for (int k = 0; k < TOPK; ++k) {
      top_logits[t * TOPK + k] = val[k];
      sel[t * TOPK + k] = idx[k];
      rwts[t * TOPK + k] = ex[k] / sum;
      selS[wid][k] = idx[k];
    }
  }
  __syncthreads();
  const int sidx = lane >> 3, jj = lane & 7;
#pragma unroll
  for (int k = 0; k < TOPK; ++k) {
    int e = selS[wid][k];
    const float* wsg = w_sgate + (size_t)e * (HD * NSG) + sidx;
    float z = 0.f;
    for (int i = 0; i < HD / 8; ++i) {
      int h = jj + 8 * i;
      z += rl[wid][h] * wsg[(size_t)h * NSG];
    }
    z += __shfl_xor(z, 1);
    z += __shfl_xor(z, 2);
    z += __shfl_xor(z, 4);
    unsigned long long bm = __ballot(z > 0.f);
    if (lane == 0) {
      unsigned b = 0;
#pragma unroll
      for (int s = 0; s < NSG; ++s) b |= (unsigned)((bm >> (s * 8)) & 1ULL) << s;
      sgq[t * TOPK + k] = b;
    }
  }
}

// ---------------- dispatch: ordered compaction per expert ----------------
__global__ __launch_bounds__(256) void dispatch_kernel(
    const int* __restrict__ sel, const float* __restrict__ rwts,
    const unsigned* __restrict__ sgq,
    int* __restrict__ tok_idx, float* __restrict__ tok_w,
    unsigned* __restrict__ sgbits, int* __restrict__ counts) {
  const int e = blockIdx.x;
  __shared__ int wcnt[4];
  __shared__ int base;
  const int tid = threadIdx.x, lane = tid & 63, wid = tid >> 6;
  if (tid == 0) base = 0;
  __syncthreads();
  for (int t0 = 0; t0 < TT; t0 += 256) {
    int t = t0 + tid;
    int hitk = -1;
#pragma unroll
    for (int k = 0; k < TOPK; ++k)
      if (sel[t * TOPK + k] == e) hitk = k;
    unsigned long long m = __ballot(hitk >= 0);
    if (lane == 0) wcnt[wid] = __popcll(m);
    __syncthreads();
    int off = base;
    for (int w = 0; w < wid; ++w) off += wcnt[w];
    int pos = off + __popcll(m & ((1ULL << lane) - 1ULL));
    if (hitk >= 0 && pos < CAPE) {
      tok_idx[e * CAPE + pos] = t;
      tok_w[e * CAPE + pos] = rwts[t * TOPK + hitk];
      sgbits[e * CAPE + pos] = sgq[t * TOPK + hitk];
    }
    __syncthreads();
    if (tid == 0) base += wcnt[0] + wcnt[1] + wcnt[2] + wcnt[3];
    __syncthreads();
  }
  if (tid == 0) counts[e] = base < CAPE ? base : CAPE;
}

// ---------------- prepass: x fp32 -> bf16 ----------------
__global__ __launch_bounds__(256) void cvt_x_kernel(const float* __restrict__ x,
                                                    unsigned short* __restrict__ xb) {
  size_t i = ((size_t)blockIdx.x * 256 + threadIdx.x) * 8;
  float4 a = *(const float4*)(x + i);
  float4 b = *(const float4*)(x + i + 4);
  us8 o = {f2bf(a.x), f2bf(a.y), f2bf(a.z), f2bf(a.w),
           f2bf(b.x), f2bf(b.y), f2bf(b.z), f2bf(b.w)};
  *(us8*)(xb + i) = o;
}

// ---------------- prepass: per-expert transpose+convert  in[R][C] f32 -> out[C][R] bf16 ----
__global__ __launch_bounds__(256) void transpose_cvt_kernel(
    const float* __restrict__ in, unsigned short* __restrict__ out, int R, int C) {
  const int e = blockIdx.z;
  const int r0 = blockIdx.x * 64, c0 = blockIdx.y * 64;
  __shared__ float t[64][65];
  const int tid = threadIdx.x;
  const float* inp = in + (size_t)e * R * C;
  {
    const int row = tid >> 4, col4 = (tid & 15) << 2;
#pragma unroll
    for (int p = 0; p < 4; ++p) {
      float4 v = *(const float4*)(inp + (size_t)(r0 + p * 16 + row) * C + c0 + col4);
      t[p * 16 + row][col4 + 0] = v.x;
      t[p * 16 + row][col4 + 1] = v.y;
      t[p * 16 + row][col4 + 2] = v.z;
      t[p * 16 + row][col4 + 3] = v.w;
    }
  }
  __syncthreads();
  {
    const int c = tid >> 2, j = tid & 3;
    us8 o0, o1;
#pragma unroll
    for (int i = 0; i < 8; ++i) o0[i] = f2bf(t[j * 16 + i][c]);
#pragma unroll
    for (int i = 0; i < 8; ++i) o1[i] = f2bf(t[j * 16 + 8 + i][c]);
    unsigned short* op = out + (size_t)e * R * C + (size_t)(c0 + c) * R + r0 + j * 16;
    *(us8*)op = o0;
    *(us8*)(op + 8) = o1;
  }
}

// ---------------- up/gate GEMM (bf16, async staging) ----------------
__global__ __launch_bounds__(256, 2) void up_gate_bf16(
    const unsigned short* __restrict__ xb, const unsigned short* __restrict__ wub,
    const unsigned short* __restrict__ wgb, const int* __restrict__ tok_idx,
    const int* __restrict__ counts, const unsigned* __restrict__ sgbits,
    unsigned short* __restrict__ act) {
  const int e = blockIdx.z;
  const int count = counts[e];
  const int m0 = blockIdx.x * 128;
  if (m0 >= count) return;
  const int n0 = blockIdx.y * 128;

  __shared__ __align__(16) unsigned short As[128 * 64];
  __shared__ __align__(16) unsigned short Bu[128 * 64];
  __shared__ __align__(16) unsigned short Bg[128 * 64];

  const int tid = threadIdx.x, lane = tid & 63, wid = tid >> 6;
  const int wr = wid >> 1, wc = wid & 1;
  const int ecap = e * CAPE;

  // staging geometry: call c covers LDS rows [c*32, c*32+32); thread -> row c*32+tid/8, blk tid&7
  const int srow = tid >> 3, sblk = tid & 7;
  const unsigned short *gA[4], *gU[4], *gG[4];
#pragma unroll
  for (int c = 0; c < 4; ++c) {
    int r = c * 32 + srow;
    int gm = m0 + r;
    int gc = gm < count ? gm : count - 1;
    int swz = (sblk ^ (r & 7)) << 3;  // bf16 elems
    gA[c] = xb + (size_t)tok_idx[ecap + gc] * HD + swz;
    gU[c] = wub + (size_t)(e * FD + n0 + r) * HD + swz;
    gG[c] = wgb + (size_t)(e * FD + n0 + r) * HD + swz;
  }
  unsigned short* lA = As + (tid << 3);
  unsigned short* lU = Bu + (tid << 3);
  unsigned short* lG = Bg + (tid << 3);

  f32x4 accU[4][4], accG[4][4];
#pragma unroll
  for (int i = 0; i < 4; ++i)
#pragma unroll
    for (int j = 0; j < 4; ++j) { accU[i][j] = (f32x4)0.f; accG[i][j] = (f32x4)0.f; }

  const int fr = lane & 15, fq = lane >> 4;
  const int frx = (fr & 7) << 3;

  for (int kt = 0; kt < HD; kt += 64) {
    __syncthreads();
#pragma unroll
    for (int c = 0; c < 4; ++c) {
      async16(gA[c] + kt, lA + c * 2048);
      async16(gU[c] + kt, lU + c * 2048);
      async16(gG[c] + kt, lG + c * 2048);
    }
    __syncthreads();
#pragma unroll
    for (int kk = 0; kk < 64; kk += 32) {
      short8 af[4], bu[4], bg[4];
      const int kphys = (kk + fq * 8) ^ frx;
#pragma unroll
      for (int mi = 0; mi < 4; ++mi)
        af[mi] = *(const short8*)(As + ((wr * 64 + mi * 16 + fr) << 6) + kphys);
#pragma unroll
      for (int ni = 0; ni < 4; ++ni) {
        bu[ni] = *(const short8*)(Bu + ((wc * 64 + ni * 16 + fr) << 6) + kphys);
        bg[ni] = *(const short8*)(Bg + ((wc * 64 + ni * 16 + fr) << 6) + kphys);
      }
#pragma unroll
      for (int mi = 0; mi < 4; ++mi)
#pragma unroll
        for (int ni = 0; ni < 4; ++ni) {
          accU[mi][ni] = __builtin_amdgcn_mfma_f32_16x16x32_bf16(af[mi], bu[ni], accU[mi][ni], 0, 0, 0);
          accG[mi][ni] = __builtin_amdgcn_mfma_f32_16x16x32_bf16(af[mi], bg[ni], accG[mi][ni], 0, 0, 0);
        }
    }
  }
#pragma unroll
  for (int mi = 0; mi < 4; ++mi) {
#pragma unroll
    for (int q = 0; q < 4; ++q) {
      int grow = m0 + wr * 64 + mi * 16 + fq * 4 + q;
      if (grow < count) {
        unsigned sg = sgbits[ecap + grow];
        unsigned short* arow = act + (size_t)(ecap + grow) * FD + n0 + wc * 64 + fr;
#pragma unroll
        for (int ni = 0; ni < 4; ++ni) {
          int gcol = n0 + wc * 64 + ni * 16 + fr;
          float a = accU[mi][ni][q] * fmaxf(accG[mi][ni][q], 0.f);
          a = ((sg >> (gcol / 96)) & 1u) ? a : 0.f;
          arow[ni * 16] = f2bf(a);
        }
      }
    }
  }
}

// ---------------- down GEMM (bf16, async staging) + weighted scatter ----------------
__global__ __launch_bounds__(256, 3) void down_bf16(
    const unsigned short* __restrict__ act, const unsigned short* __restrict__ wdb,
    const int* __restrict__ tok_idx, const float* __restrict__ tok_w,
    const int* __restrict__ counts, float* __restrict__ outF) {
  const int e = blockIdx.z;
  const int count = counts[e];
  const int m0 = blockIdx.x * 128;
  if (m0 >= count) return;
  const int n0 = blockIdx.y * 128;

  __shared__ __align__(16) unsigned short As[128 * 64];
  __shared__ __align__(16) unsigned short Bs[128 * 64];

  const int tid = threadIdx.x, lane = tid & 63, wid = tid >> 6;
  const int wr = wid >> 1, wc = wid & 1;
  const int ecap = e * CAPE;

  const int srow = tid >> 3, sblk = tid & 7;
  const unsigned short *gA[4], *gB[4];
#pragma unroll
  for (int c = 0; c < 4; ++c) {
    int r = c * 32 + srow;
    int swz = (sblk ^ (r & 7)) << 3;
    gA[c] = act + (size_t)(ecap + m0 + r) * FD + swz;
    gB[c] = wdb + (size_t)(e * HD + n0 + r) * FD + swz;
  }
  unsigned short* lA = As + (tid << 3);
  unsigned short* lB = Bs + (tid << 3);

  f32x4 accD[4][4];
#pragma unroll
  for (int i = 0; i < 4; ++i)
#pragma unroll
    for (int j = 0; j < 4; ++j) accD[i][j] = (f32x4)0.f;

  const int fr = lane & 15, fq = lane >> 4;
  const int frx = (fr & 7) << 3;

  for (int kt = 0; kt < FD; kt += 64) {
    __syncthreads();
#pragma unroll
    for (int c = 0; c < 4; ++c) {
      async16(gA[c] + kt, lA + c * 2048);
      async16(gB[c] + kt, lB + c * 2048);
    }
    __syncthreads();
#pragma unroll
    for (int kk = 0; kk < 64; kk += 32) {
      short8 af[4], bb[4];
      const int kphys = (kk + fq * 8) ^ frx;
#pragma unroll
      for (int mi = 0; mi < 4; ++mi)
        af[mi] = *(const short8*)(As + ((wr * 64 + mi * 16 + fr) << 6) + kphys);
#pragma unroll
      for (int ni = 0; ni < 4; ++ni)
        bb[ni] = *(const short8*)(Bs + ((wc * 64 + ni * 16 + fr) << 6) + kphys);
#pragma unroll
      for (int mi = 0; mi < 4; ++mi)
#pragma unroll
        for (int ni = 0; ni < 4; ++ni)
          accD[mi][ni] = __builtin_amdgcn_mfma_f32_16x16x32_bf16(af[mi], bb[ni], accD[mi][ni], 0, 0, 0);
    }
  }
#pragma unroll
  for (int mi = 0; mi < 4; ++mi) {
#pragma unroll
    for (int q = 0; q < 4; ++q) {
      int grow = m0 + wr * 64 + mi * 16 + fq * 4 + q;
      if (grow < count) {
        float wgt = tok_w[ecap + grow];
        float* dst = outF + (size_t)tok_idx[ecap + grow] * HD + n0 + wc * 64 + fr;
#pragma unroll
        for (int ni = 0; ni < 4; ++ni)
          atomicAdd(dst + ni * 16, accD[mi][ni][q] * wgt);
      }
    }
  }
}

// ================= fallback fp32 path (round-1 kernels, known-good) =================
__global__ __launch_bounds__(256, 2) void up_gate_kernel(
    const float* __restrict__ x, const float* __restrict__ w_up,
    const float* __restrict__ w_gate, const int* __restrict__ tok_idx,
    const int* __restrict__ counts, const unsigned* __restrict__ sgbits,
    unsigned short* __restrict__ act) {
  const int e = blockIdx.z;
  const int count = counts[e];
  const int m0 = blockIdx.x * 128;
  if (m0 >= count) return;
  const int n0 = blockIdx.y * 128;
  __shared__ __align__(16) unsigned short As[128 * 64];
  __shared__ __align__(16) unsigned short Bu[128 * 64];
  __shared__ __align__(16) unsigned short Bg[128 * 64];
  const int tid = threadIdx.x;
  const int lane = tid & 63, wid = tid >> 6;
  const int wr = wid >> 1, wc = wid & 1;
  const int ecap = e * CAPE;
  const int art = tid >> 4, acq = tid & 15;
  const float* aptr[8];
#pragma unroll
  for (int p = 0; p < 8; ++p) {
    int gm = m0 + p * 16 + art;
    int gc = gm < count ? gm : count - 1;
    aptr[p] = x + (size_t)tok_idx[ecap + gc] * HD + acq * 4;
  }
  const int bn = tid & 127;
  const int bkh = (tid >> 7) << 5;
  const float* upP = w_up + (size_t)e * HD * FD + n0 + bn;
  const float* gaP = w_gate + (size_t)e * HD * FD + n0 + bn;
  unsigned short* BuW = Bu + (bn << 6);
  unsigned short* BgW = Bg + (bn << 6);
  const int bxor = (bn & 7) << 3;
  f32x4 accU[4][4], accG[4][4];
#pragma unroll
  for (int i = 0; i < 4; ++i)
#pragma unroll
    for (int j = 0; j < 4; ++j) { accU[i][j] = (f32x4)0.f; accG[i][j] = (f32x4)0.f; }
  const int fr = lane & 15, fq = lane >> 4;
  const int frx = (fr & 7) << 3;
  for (int kt = 0; kt < HD; kt += 64) {
    __syncthreads();
#pragma unroll
    for (int p = 0; p < 8; ++p) {
      float4 v = *(const float4*)(aptr[p] + kt);
      us4 o = {f2bf(v.x), f2bf(v.y), f2bf(v.z), f2bf(v.w)};
      *(us4*)(As + SWZ(p * 16 + art, acq * 4)) = o;
    }
#pragma unroll
    for (int j2 = 0; j2 < 8; ++j2) {
      int k0 = bkh + j2 * 4;
      const float* u0 = upP + (size_t)(kt + k0) * FD;
      us4 ou = {f2bf(u0[0]), f2bf(u0[FD]), f2bf(u0[2 * FD]), f2bf(u0[3 * FD])};
      *(us4*)(BuW + (k0 ^ bxor)) = ou;
      const float* g0 = gaP + (size_t)(kt + k0) * FD;
      us4 og = {f2bf(g0[0]), f2bf(g0[FD]), f2bf(g0[2 * FD]), f2bf(g0[3 * FD])};
      *(us4*)(BgW + (k0 ^ bxor)) = og;
    }
    __syncthreads();
#pragma unroll
    for (int kk = 0; kk < 64; kk += 32) {
      short8 af[4], bu[4], bg[4];
      const int kphys = (kk + fq * 8) ^ frx;
#pragma unroll
      for (int mi = 0; mi < 4; ++mi)
        af[mi] = *(const short8*)(As + ((wr * 64 + mi * 16 + fr) << 6) + kphys);
#pragma unroll
      for (int ni = 0; ni < 4; ++ni) {
        bu[ni] = *(const short8*)(Bu + ((wc * 64 + ni * 16 + fr) << 6) + kphys);
        bg[ni] = *(const short8*)(Bg + ((wc * 64 + ni * 16 + fr) << 6) + kphys);
      }
#pragma unroll
      for (int mi = 0; mi < 4; ++mi)
#pragma unroll
        for (int ni = 0; ni < 4; ++ni) {
          accU[mi][ni] = __builtin_amdgcn_mfma_f32_16x16x32_bf16(af[mi], bu[ni], accU[mi][ni], 0, 0, 0);
          accG[mi][ni] = __builtin_amdgcn_mfma_f32_16x16x32_bf16(af[mi], bg[ni], accG[mi][ni], 0, 0, 0);
        }
    }
  }
#pragma unroll
  for (int mi = 0; mi < 4; ++mi) {
#pragma unroll
    for (int q = 0; q < 4; ++q) {
      int grow = m0 + wr * 64 + mi * 16 + fq * 4 + q;
      if (grow < count) {
        unsigned sg = sgbits[ecap + grow];
        unsigned short* arow = act + (size_t)(ecap + grow) * FD + n0 + wc * 64 + fr;
#pragma unroll
        for (int ni = 0; ni < 4; ++ni) {
          int gcol = n0 + wc * 64 + ni * 16 + fr;
          float a = accU[mi][ni][q] * fmaxf(accG[mi][ni][q], 0.f);
          a = ((sg >> (gcol / 96)) & 1u) ? a : 0.f;
          arow[ni * 16] = f2bf(a);
        }
      }
    }
  }
}

__global__ __launch_bounds__(256, 2) void down_kernel(
    const unsigned short* __restrict__ act, const float* __restrict__ w_down,
    const int* __restrict__ tok_idx, const float* __restrict__ tok_w,
    const int* __restrict__ counts, float* __restrict__ outF) {
  const int e = blockIdx.z;
  const int count = counts[e];
  const int m0 = blockIdx.x * 128;
  if (m0 >= count) return;
  const int n0 = blockIdx.y * 128;
  __shared__ __align__(16) unsigned short As[128 * 64];
  __shared__ __align__(16) unsigned short Bs[128 * 64];
  const int tid = threadIdx.x, lane = tid & 63, wid = tid >> 6;
  const int wr = wid >> 1, wc = wid & 1;
  const int ecap = e * CAPE;
  const int art = tid >> 3, acq = tid & 7;
  const int bn = tid & 127;
  const int bkh = (tid >> 7) << 5;
  const float* dnP = w_down + (size_t)e * FD * HD + n0 + bn;
  unsigned short* BsW = Bs + (bn << 6);
  const int bxor = (bn & 7) << 3;
  f32x4 accD[4][4];
#pragma unroll
  for (int i = 0; i < 4; ++i)
#pragma unroll
    for (int j = 0; j < 4; ++j) accD[i][j] = (f32x4)0.f;
  const int fr = lane & 15, fq = lane >> 4;
  const int frx = (fr & 7) << 3;
  for (int kt = 0; kt < FD; kt += 64) {
    __syncthreads();
#pragma unroll
    for (int p = 0; p < 4; ++p) {
      int row = p * 32 + art;
      uint4 v = *(const uint4*)(act + (size_t)(ecap + m0 + row) * FD + kt + acq * 8);
      *(uint4*)(As + SWZ(row, acq * 8)) = v;
    }
#pragma unroll
    for (int j2 = 0; j2 < 8; ++j2) {
      int k0 = bkh + j2 * 4;
      const float* d0 = dnP + (size_t)(kt + k0) * HD;
      us4 o = {f2bf(d0[0]), f2bf(d0[HD]), f2bf(d0[2 * HD]), f2bf(d0[3 * HD])};
      *(us4*)(BsW + (k0 ^ bxor)) = o;
    }
    __syncthreads();
#pragma unroll
    for (int kk = 0; kk < 64; kk += 32) {
      short8 af[4], bb[4];
      const int kphys = (kk + fq * 8) ^ frx;
#pragma unroll
      for (int mi = 0; mi < 4; ++mi)
        af[mi] = *(const short8*)(As + ((wr * 64 + mi * 16 + fr) << 6) + kphys);
#pragma unroll
      for (int ni = 0; ni < 4; ++ni)
        bb[ni] = *(const short8*)(Bs + ((wc * 64 + ni * 16 + fr) << 6) + kphys);
#pragma unroll
      for (int mi = 0; mi < 4; ++mi)
#pragma unroll
        for (int ni = 0; ni < 4; ++ni)
          accD[mi][ni] = __builtin_amdgcn_mfma_f32_16x16x32_bf16(af[mi], bb[ni], accD[mi][ni], 0, 0, 0);
    }
  }
#pragma unroll
  for (int mi = 0; mi < 4; ++mi) {
#pragma unroll
    for (int q = 0; q < 4; ++q) {
      int grow = m0 + wr * 64 + mi * 16 + fq * 4 + q;
      if (grow < count) {
        float wgt = tok_w[ecap + grow];
        float* dst = outF + (size_t)tok_idx[ecap + grow] * HD + n0 + wc * 64 + fr;
#pragma unroll
        for (int ni = 0; ni < 4; ++ni)
          atomicAdd(dst + ni * 16, accD[mi][ni][q] * wgt);
      }
    }
  }
}

extern "C" void kernel_launch(void* const* d_in, const int* in_sizes, int n_in,
                              void* d_out, int out_size, void* d_ws, size_t ws_size,
                              hipStream_t stream) {
  const float* rin = (const float*)d_in[0];
  const float* x = (const float*)d_in[1];
  const float* w_router = (const float*)d_in[2];
  const float* w_up = (const float*)d_in[3];
  const float* w_gate = (const float*)d_in[4];
  const float* w_down = (const float*)d_in[5];
  const float* w_sg = (const float*)d_in[6];
  float* outF = (float*)d_out;
  float* top_logits = outF + (size_t)TT * HD;

  char* ws = (char*)d_ws;
  int* sel = (int*)(ws + 0);
  float* rwts = (float*)(ws + (64 << 10));
  unsigned* sgq = (unsigned*)(ws + (128 << 10));
  int* tidx = (int*)(ws + (192 << 10));
  float* tw = (float*)(ws + (320 << 10));
  unsigned* sgb = (unsigned*)(ws + (448 << 10));
  int* counts = (int*)(ws + (576 << 10));
  unsigned short* act = (unsigned short*)(ws + (1 << 20));  // 48 MB

  const size_t OFF_XB = (size_t)52 << 20;                    // 16 MB
  const size_t OFF_WU = (size_t)69 << 20;                    // 96 MB
  const size_t OFF_WG = OFF_WU + (size_t)NE * HD * FD * 2;   // 96 MB
  const size_t OFF_WD = OFF_WG + (size_t)NE * HD * FD * 2;   // 96 MB
  const size_t NEED = OFF_WD + (size_t)NE * HD * FD * 2 + 1024;

  hipMemsetAsync(d_out, 0, (size_t)TT * HD * sizeof(float), stream);
  router_kernel<<<TT / 4, 256, 0, stream>>>(rin, w_router, w_sg, top_logits, sel, rwts, sgq);
  dispatch_kernel<<<NE, 256, 0, stream>>>(sel, rwts, sgq, tidx, tw, sgb, counts);

  if (ws_size >= NEED) {
    unsigned short* xb = (unsigned short*)(ws + OFF_XB);
    unsigned short* wub = (unsigned short*)(ws + OFF_WU);
    unsigned short* wgb = (unsigned short*)(ws + OFF_WG);
    unsigned short* wdb = (unsigned short*)(ws + OFF_WD);
    cvt_x_kernel<<<(TT * HD) / (256 * 8), 256, 0, stream>>>(x, xb);
    // w_up [E][H][F] -> [E][F][H]
    transpose_cvt_kernel<<<dim3(HD / 64, FD / 64, NE), 256, 0, stream>>>(w_up, wub, HD, FD);
    transpose_cvt_kernel<<<dim3(HD / 64, FD / 64, NE), 256, 0, stream>>>(w_gate, wgb, HD, FD);
    // w_down [E][F][H] -> [E][H][F]
    transpose_cvt_kernel<<<dim3(FD / 64, HD / 64, NE), 256, 0, stream>>>(w_down, wdb, FD, HD);
    up_gate_bf16<<<dim3(CAPE / 128, FD / 128, NE), 256, 0, stream>>>(xb, wub, wgb, tidx, counts, sgb, act);
    down_bf16<<<dim3(CAPE / 128, HD / 128, NE), 256, 0, stream>>>(act, wdb, tidx, tw, counts, outF);
  } else {
    up_gate_kernel<<<dim3(CAPE / 128, FD / 128, NE), 256, 0, stream>>>(x, w_up, w_gate, tidx, counts, sgb, act);
    down_kernel<<<dim3(CAPE / 128, HD / 128, NE), 256, 0, stream>>>(act, w_down, tidx, tw, counts, outF);
  }
}

// Round 3
// 747.872 us; speedup vs baseline: 3.1153x; 1.3013x over previous
//
#include <hip/hip_runtime.h>

#define TT 4096
#define HD 2048
#define FD 768
#define NE 32
#define TOPK 4
#define NSG 8
#define CAPE 1024

typedef __attribute__((ext_vector_type(8))) short short8;
typedef __attribute__((ext_vector_type(4))) float f32x4;
typedef __attribute__((ext_vector_type(4))) unsigned short us4;
typedef __attribute__((ext_vector_type(8))) unsigned short us8;

// XOR-swizzled LDS index for [row][64] bf16 tiles
#define SWZ(r, k) (((r) << 6) + ((k) ^ (((r) & 7) << 3)))

__device__ __forceinline__ unsigned short f2bf(float f) {
  unsigned u = __builtin_bit_cast(unsigned, f);
  u += 0x7FFFu + ((u >> 16) & 1u);
  return (unsigned short)(u >> 16);
}

__device__ __forceinline__ void async16(const void* g, void* l) {
  __builtin_amdgcn_global_load_lds(
      (const __attribute__((address_space(1))) unsigned int*)g,
      (__attribute__((address_space(3))) unsigned int*)l, 16, 0, 0);
}

// ---------------- w_router [H][E] -> wrt [E][H] (fp32, tiny) ----------------
__global__ __launch_bounds__(256) void wrt_kernel(const float* __restrict__ w_router,
                                                  float* __restrict__ wrt) {
  int idx = blockIdx.x * 256 + threadIdx.x;  // 65536 elements
  int e = idx >> 11, h = idx & 2047;
  wrt[idx] = w_router[h * NE + e];
}

// ---------------- logits fp32 GEMM: [TT,HD] x [HD,NE] -> [TT,NE] ----------------
#define LSTR 68
__global__ __launch_bounds__(256) void logits_kernel(
    const float* __restrict__ rin, const float* __restrict__ wrt,
    float* __restrict__ logits) {
  __shared__ float As[16 * LSTR];
  __shared__ float Bs[32 * LSTR];
  const int tid = threadIdx.x;
  const int t0 = blockIdx.x * 16;
  const int tp = tid >> 4, eg = tid & 15;
  f32x4 acc0 = (f32x4)0.f, acc1 = (f32x4)0.f;
  for (int kt = 0; kt < HD; kt += 64) {
    __syncthreads();
    {  // stage A: 16 x 64 floats, 1 f4/thread
      int row = tid >> 4, col = (tid & 15) * 4;
      *(f32x4*)&As[row * LSTR + col] =
          *(const f32x4*)&rin[(size_t)(t0 + row) * HD + kt + col];
    }
    {  // stage B: 32 x 64 floats, 2 f4/thread
      int e = tid >> 3, col = (tid & 7) * 8;
      *(f32x4*)&Bs[e * LSTR + col] = *(const f32x4*)&wrt[(size_t)e * HD + kt + col];
      *(f32x4*)&Bs[e * LSTR + col + 4] =
          *(const f32x4*)&wrt[(size_t)e * HD + kt + col + 4];
    }
    __syncthreads();
#pragma unroll
    for (int k4 = 0; k4 < 16; ++k4) {
      f32x4 a = *(const f32x4*)&As[tp * LSTR + k4 * 4];
      f32x4 b0 = *(const f32x4*)&Bs[eg * LSTR + k4 * 4];
      f32x4 b1 = *(const f32x4*)&Bs[(eg + 16) * LSTR + k4 * 4];
      acc0 += a * b0;
      acc1 += a * b1;
    }
  }
  logits[(t0 + tp) * NE + eg] = acc0[0] + acc0[1] + acc0[2] + acc0[3];
  logits[(t0 + tp) * NE + eg + 16] = acc1[0] + acc1[1] + acc1[2] + acc1[3];
}

// ---------------- top-4 + softmax per token ----------------
__global__ __launch_bounds__(256) void topk_kernel(
    const float* __restrict__ logits, float* __restrict__ top_logits,
    int* __restrict__ sel, float* __restrict__ rwts) {
  __shared__ float lg[256 * 33];
  const int tid = threadIdx.x;
  const int t0 = blockIdx.x * 256;
#pragma unroll
  for (int i = 0; i < 8; ++i) {
    int fi = tid + i * 256;  // f4 index within 2048 f4s
    f32x4 v = *(const f32x4*)&logits[(size_t)t0 * NE + fi * 4];
    int tok = fi >> 3, e0 = (fi & 7) * 4;
#pragma unroll
    for (int c = 0; c < 4; ++c) lg[tok * 33 + e0 + c] = v[c];
  }
  __syncthreads();
  const float* row = &lg[tid * 33];
  float val[TOPK];
  int idx[TOPK];
  unsigned used = 0;
#pragma unroll
  for (int k = 0; k < TOPK; ++k) {
    float best = -1e30f;
    int bi = 0;
    for (int e = 0; e < NE; ++e) {
      float v = row[e];
      if (!((used >> e) & 1u) && v > best) { best = v; bi = e; }
    }
    used |= 1u << bi;
    val[k] = best;
    idx[k] = bi;
  }
  float ex[TOPK], sum = 0.f;
#pragma unroll
  for (int k = 0; k < TOPK; ++k) { ex[k] = expf(val[k] - val[0]); sum += ex[k]; }
  int t = t0 + tid;
#pragma unroll
  for (int k = 0; k < TOPK; ++k) {
    top_logits[t * TOPK + k] = val[k];
    sel[t * TOPK + k] = idx[k];
    rwts[t * TOPK + k] = ex[k] / sum;
  }
}

// ---------------- dispatch: ordered compaction per expert ----------------
__global__ __launch_bounds__(256) void dispatch_kernel(
    const int* __restrict__ sel, const float* __restrict__ rwts,
    int* __restrict__ tok_idx, float* __restrict__ tok_w, int* __restrict__ counts) {
  const int e = blockIdx.x;
  __shared__ int wcnt[4];
  __shared__ int base;
  const int tid = threadIdx.x, lane = tid & 63, wid = tid >> 6;
  if (tid == 0) base = 0;
  __syncthreads();
  for (int t0 = 0; t0 < TT; t0 += 256) {
    int t = t0 + tid;
    int hitk = -1;
#pragma unroll
    for (int k = 0; k < TOPK; ++k)
      if (sel[t * TOPK + k] == e) hitk = k;
    unsigned long long m = __ballot(hitk >= 0);
    if (lane == 0) wcnt[wid] = __popcll(m);
    __syncthreads();
    int off = base;
    for (int w = 0; w < wid; ++w) off += wcnt[w];
    int pos = off + __popcll(m & ((1ULL << lane) - 1ULL));
    if (hitk >= 0 && pos < CAPE) {
      tok_idx[e * CAPE + pos] = t;
      tok_w[e * CAPE + pos] = rwts[t * TOPK + hitk];
    }
    __syncthreads();
    if (tid == 0) base += wcnt[0] + wcnt[1] + wcnt[2] + wcnt[3];
    __syncthreads();
  }
  if (tid == 0) counts[e] = base < CAPE ? base : CAPE;
}

// ---------------- secondary gate per (expert, slot): w_sgate[e] staged in LDS ----------
__global__ __launch_bounds__(256) void sgate_kernel(
    const float* __restrict__ rin, const float* __restrict__ w_sgate,
    const int* __restrict__ tok_idx, const int* __restrict__ counts,
    unsigned* __restrict__ sgbits) {
  const int e = blockIdx.y;
  const int count = counts[e];
  const int s0 = blockIdx.x * 128;
  if (s0 >= count || count == 0) return;
  __shared__ float wsgS[2048 * 9];  // 72 KB, pad 9 => conflict-free scalar reads
  const int tid = threadIdx.x, lane = tid & 63, wid = tid >> 6;
  const float* wsg = w_sgate + (size_t)e * (HD * NSG);
#pragma unroll
  for (int p = 0; p < 8; ++p) {
    int row = p * 256 + tid;
    f32x4 v0 = *(const f32x4*)&wsg[row * 8];
    f32x4 v1 = *(const f32x4*)&wsg[row * 8 + 4];
#pragma unroll
    for (int c = 0; c < 4; ++c) {
      wsgS[row * 9 + c] = v0[c];
      wsgS[row * 9 + 4 + c] = v1[c];
    }
  }
  __syncthreads();
  const int base = s0 + wid * 32;
  for (int j = 0; j < 16; ++j) {
    int sA = base + j, sB = base + j + 16;
    if (sA >= count) break;
    int tokA = tok_idx[e * CAPE + sA];
    int tokB = tok_idx[e * CAPE + (sB < count ? sB : sA)];
    float zA[8], zB[8];
#pragma unroll
    for (int s = 0; s < 8; ++s) { zA[s] = 0.f; zB[s] = 0.f; }
    const float* rAp = rin + (size_t)tokA * HD;
    const float* rBp = rin + (size_t)tokB * HD;
#pragma unroll 4
    for (int i = 0; i < 32; ++i) {
      int h = lane + 64 * i;
      float rA = rAp[h];
      float rB = rBp[h];
#pragma unroll
      for (int s = 0; s < 8; ++s) {
        float w = wsgS[h * 9 + s];
        zA[s] += rA * w;
        zB[s] += rB * w;
      }
    }
#pragma unroll
    for (int s = 0; s < 8; ++s) {
#pragma unroll
      for (int d = 1; d < 64; d <<= 1) {
        zA[s] += __shfl_xor(zA[s], d);
        zB[s] += __shfl_xor(zB[s], d);
      }
    }
    if (lane == 0) {
      unsigned bA = 0, bB = 0;
#pragma unroll
      for (int s = 0; s < 8; ++s) {
        bA |= ((unsigned)(zA[s] > 0.f)) << s;
        bB |= ((unsigned)(zB[s] > 0.f)) << s;
      }
      sgbits[e * CAPE + sA] = bA;
      if (sB < count) sgbits[e * CAPE + sB] = bB;
    }
  }
}

// ---------------- prepass: x fp32 -> bf16 ----------------
__global__ __launch_bounds__(256) void cvt_x_kernel(const float* __restrict__ x,
                                                    unsigned short* __restrict__ xb) {
  size_t i = ((size_t)blockIdx.x * 256 + threadIdx.x) * 8;
  float4 a = *(const float4*)(x + i);
  float4 b = *(const float4*)(x + i + 4);
  us8 o = {f2bf(a.x), f2bf(a.y), f2bf(a.z), f2bf(a.w),
           f2bf(b.x), f2bf(b.y), f2bf(b.z), f2bf(b.w)};
  *(us8*)(xb + i) = o;
}

// ---------------- prepass: per-expert transpose+convert in[R][C] f32 -> out[C][R] bf16 ---
__global__ __launch_bounds__(256) void transpose_cvt_kernel(
    const float* __restrict__ in, unsigned short* __restrict__ out, int R, int C) {
  const int e = blockIdx.z;
  const int r0 = blockIdx.x * 64, c0 = blockIdx.y * 64;
  __shared__ float t[64][65];
  const int tid = threadIdx.x;
  const float* inp = in + (size_t)e * R * C;
  {
    const int row = tid >> 4, col4 = (tid & 15) << 2;
#pragma unroll
    for (int p = 0; p < 4; ++p) {
      float4 v = *(const float4*)(inp + (size_t)(r0 + p * 16 + row) * C + c0 + col4);
      t[p * 16 + row][col4 + 0] = v.x;
      t[p * 16 + row][col4 + 1] = v.y;
      t[p * 16 + row][col4 + 2] = v.z;
      t[p * 16 + row][col4 + 3] = v.w;
    }
  }
  __syncthreads();
  {
    const int c = tid >> 2, j = tid & 3;
    us8 o0, o1;
#pragma unroll
    for (int i = 0; i < 8; ++i) o0[i] = f2bf(t[j * 16 + i][c]);
#pragma unroll
    for (int i = 0; i < 8; ++i) o1[i] = f2bf(t[j * 16 + 8 + i][c]);
    unsigned short* op = out + (size_t)e * R * C + (size_t)(c0 + c) * R + r0 + j * 16;
    *(us8*)op = o0;
    *(us8*)(op + 8) = o1;
  }
}

// ---------------- up/gate GEMM (bf16, async staging) ----------------
__global__ __launch_bounds__(256, 2) void up_gate_bf16(
    const unsigned short* __restrict__ xb, const unsigned short* __restrict__ wub,
    const unsigned short* __restrict__ wgb, const int* __restrict__ tok_idx,
    const int* __restrict__ counts, const unsigned* __restrict__ sgbits,
    unsigned short* __restrict__ act) {
  const int e = blockIdx.z;
  const int count = counts[e];
  const int m0 = blockIdx.x * 128;
  if (m0 >= count) return;
  const int n0 = blockIdx.y * 128;

  __shared__ __align__(16) unsigned short As[128 * 64];
  __shared__ __align__(16) unsigned short Bu[128 * 64];
  __shared__ __align__(16) unsigned short Bg[128 * 64];

  const int tid = threadIdx.x, lane = tid & 63, wid = tid >> 6;
  const int wr = wid >> 1, wc = wid & 1;
  const int ecap = e * CAPE;

  const int srow = tid >> 3, sblk = tid & 7;
  const unsigned short *gA[4], *gU[4], *gG[4];
#pragma unroll
  for (int c = 0; c < 4; ++c) {
    int r = c * 32 + srow;
    int gm = m0 + r;
    int gc = gm < count ? gm : count - 1;
    int swz = (sblk ^ (r & 7)) << 3;
    gA[c] = xb + (size_t)tok_idx[ecap + gc] * HD + swz;
    gU[c] = wub + (size_t)(e * FD + n0 + r) * HD + swz;
    gG[c] = wgb + (size_t)(e * FD + n0 + r) * HD + swz;
  }
  unsigned short* lA = As + (tid << 3);
  unsigned short* lU = Bu + (tid << 3);
  unsigned short* lG = Bg + (tid << 3);

  f32x4 accU[4][4], accG[4][4];
#pragma unroll
  for (int i = 0; i < 4; ++i)
#pragma unroll
    for (int j = 0; j < 4; ++j) { accU[i][j] = (f32x4)0.f; accG[i][j] = (f32x4)0.f; }

  const int fr = lane & 15, fq = lane >> 4;
  const int frx = (fr & 7) << 3;

  for (int kt = 0; kt < HD; kt += 64) {
    __syncthreads();
#pragma unroll
    for (int c = 0; c < 4; ++c) {
      async16(gA[c] + kt, lA + c * 2048);
      async16(gU[c] + kt, lU + c * 2048);
      async16(gG[c] + kt, lG + c * 2048);
    }
    __syncthreads();
#pragma unroll
    for (int kk = 0; kk < 64; kk += 32) {
      short8 af[4], bu[4], bg[4];
      const int kphys = (kk + fq * 8) ^ frx;
#pragma unroll
      for (int mi = 0; mi < 4; ++mi)
        af[mi] = *(const short8*)(As + ((wr * 64 + mi * 16 + fr) << 6) + kphys);
#pragma unroll
      for (int ni = 0; ni < 4; ++ni) {
        bu[ni] = *(const short8*)(Bu + ((wc * 64 + ni * 16 + fr) << 6) + kphys);
        bg[ni] = *(const short8*)(Bg + ((wc * 64 + ni * 16 + fr) << 6) + kphys);
      }
#pragma unroll
      for (int mi = 0; mi < 4; ++mi)
#pragma unroll
        for (int ni = 0; ni < 4; ++ni) {
          accU[mi][ni] = __builtin_amdgcn_mfma_f32_16x16x32_bf16(af[mi], bu[ni], accU[mi][ni], 0, 0, 0);
          accG[mi][ni] = __builtin_amdgcn_mfma_f32_16x16x32_bf16(af[mi], bg[ni], accG[mi][ni], 0, 0, 0);
        }
    }
  }
#pragma unroll
  for (int mi = 0; mi < 4; ++mi) {
#pragma unroll
    for (int q = 0; q < 4; ++q) {
      int grow = m0 + wr * 64 + mi * 16 + fq * 4 + q;
      if (grow < count) {
        unsigned sg = sgbits[ecap + grow];
        unsigned short* arow = act + (size_t)(ecap + grow) * FD + n0 + wc * 64 + fr;
#pragma unroll
        for (int ni = 0; ni < 4; ++ni) {
          int gcol = n0 + wc * 64 + ni * 16 + fr;
          float a = accU[mi][ni][q] * fmaxf(accG[mi][ni][q], 0.f);
          a = ((sg >> (gcol / 96)) & 1u) ? a : 0.f;
          arow[ni * 16] = f2bf(a);
        }
      }
    }
  }
}

// ---------------- down GEMM (bf16, async staging) + weighted scatter ----------------
__global__ __launch_bounds__(256, 3) void down_bf16(
    const unsigned short* __restrict__ act, const unsigned short* __restrict__ wdb,
    const int* __restrict__ tok_idx, const float* __restrict__ tok_w,
    const int* __restrict__ counts, float* __restrict__ outF) {
  const int e = blockIdx.z;
  const int count = counts[e];
  const int m0 = blockIdx.x * 128;
  if (m0 >= count) return;
  const int n0 = blockIdx.y * 128;

  __shared__ __align__(16) unsigned short As[128 * 64];
  __shared__ __align__(16) unsigned short Bs[128 * 64];

  const int tid = threadIdx.x, lane = tid & 63, wid = tid >> 6;
  const int wr = wid >> 1, wc = wid & 1;
  const int ecap = e * CAPE;

  const int srow = tid >> 3, sblk = tid & 7;
  const unsigned short *gA[4], *gB[4];
#pragma unroll
  for (int c = 0; c < 4; ++c) {
    int r = c * 32 + srow;
    int swz = (sblk ^ (r & 7)) << 3;
    gA[c] = act + (size_t)(ecap + m0 + r) * FD + swz;
    gB[c] = wdb + (size_t)(e * HD + n0 + r) * FD + swz;
  }
  unsigned short* lA = As + (tid << 3);
  unsigned short* lB = Bs + (tid << 3);

  f32x4 accD[4][4];
#pragma unroll
  for (int i = 0; i < 4; ++i)
#pragma unroll
    for (int j = 0; j < 4; ++j) accD[i][j] = (f32x4)0.f;

  const int fr = lane & 15, fq = lane >> 4;
  const int frx = (fr & 7) << 3;

  for (int kt = 0; kt < FD; kt += 64) {
    __syncthreads();
#pragma unroll
    for (int c = 0; c < 4; ++c) {
      async16(gA[c] + kt, lA + c * 2048);
      async16(gB[c] + kt, lB + c * 2048);
    }
    __syncthreads();
#pragma unroll
    for (int kk = 0; kk < 64; kk += 32) {
      short8 af[4], bb[4];
      const int kphys = (kk + fq * 8) ^ frx;
#pragma unroll
      for (int mi = 0; mi < 4; ++mi)
        af[mi] = *(const short8*)(As + ((wr * 64 + mi * 16 + fr) << 6) + kphys);
#pragma unroll
      for (int ni = 0; ni < 4; ++ni)
        bb[ni] = *(const short8*)(Bs + ((wc * 64 + ni * 16 + fr) << 6) + kphys);
#pragma unroll
      for (int mi = 0; mi < 4; ++mi)
#pragma unroll
        for (int ni = 0; ni < 4; ++ni)
          accD[mi][ni] = __builtin_amdgcn_mfma_f32_16x16x32_bf16(af[mi], bb[ni], accD[mi][ni], 0, 0, 0);
    }
  }
#pragma unroll
  for (int mi = 0; mi < 4; ++mi) {
#pragma unroll
    for (int q = 0; q < 4; ++q) {
      int grow = m0 + wr * 64 + mi * 16 + fq * 4 + q;
      if (grow < count) {
        float wgt = tok_w[ecap + grow];
        float* dst = outF + (size_t)tok_idx[ecap + grow] * HD + n0 + wc * 64 + fr;
#pragma unroll
        for (int ni = 0; ni < 4; ++ni)
          atomicAdd(dst + ni * 16, accD[mi][ni][q] * wgt);
      }
    }
  }
}

extern "C" void kernel_launch(void* const* d_in, const int* in_sizes, int n_in,
                              void* d_out, int out_size, void* d_ws, size_t ws_size,
                              hipStream_t stream) {
  const float* rin = (const float*)d_in[0];
  const float* x = (const float*)d_in[1];
  const float* w_router = (const float*)d_in[2];
  const float* w_up = (const float*)d_in[3];
  const float* w_gate = (const float*)d_in[4];
  const float* w_down = (const float*)d_in[5];
  const float* w_sg = (const float*)d_in[6];
  float* outF = (float*)d_out;
  float* top_logits = outF + (size_t)TT * HD;

  char* ws = (char*)d_ws;
  int* sel = (int*)(ws + 0);                      // 64 KB
  float* rwts = (float*)(ws + (64 << 10));        // 64 KB
  int* tidx = (int*)(ws + (192 << 10));           // 128 KB
  float* tw = (float*)(ws + (320 << 10));         // 128 KB
  unsigned* sgb = (unsigned*)(ws + (448 << 10));  // 128 KB
  int* counts = (int*)(ws + (576 << 10));
  float* logits = (float*)(ws + (640 << 10));     // 512 KB
  unsigned short* act = (unsigned short*)(ws + ((size_t)2 << 20));   // 48 MB
  float* wrt = (float*)(ws + ((size_t)51 << 20));                    // 256 KB
  unsigned short* xb = (unsigned short*)(ws + ((size_t)52 << 20));   // 16 MB
  unsigned short* wub = (unsigned short*)(ws + ((size_t)69 << 20));  // 96 MB
  unsigned short* wgb = wub + (size_t)NE * HD * FD;                  // 96 MB
  unsigned short* wdb = wgb + (size_t)NE * HD * FD;                  // 96 MB

  hipMemsetAsync(d_out, 0, (size_t)TT * HD * sizeof(float), stream);

  // routing front-end
  wrt_kernel<<<256, 256, 0, stream>>>(w_router, wrt);
  logits_kernel<<<TT / 16, 256, 0, stream>>>(rin, wrt, logits);
  topk_kernel<<<TT / 256, 256, 0, stream>>>(logits, top_logits, sel, rwts);
  dispatch_kernel<<<NE, 256, 0, stream>>>(sel, rwts, tidx, tw, counts);
  sgate_kernel<<<dim3(CAPE / 128, NE), 256, 0, stream>>>(rin, w_sg, tidx, counts, sgb);

  // bf16 conversion prepasses
  cvt_x_kernel<<<(TT * HD) / (256 * 8), 256, 0, stream>>>(x, xb);
  transpose_cvt_kernel<<<dim3(HD / 64, FD / 64, NE), 256, 0, stream>>>(w_up, wub, HD, FD);
  transpose_cvt_kernel<<<dim3(HD / 64, FD / 64, NE), 256, 0, stream>>>(w_gate, wgb, HD, FD);
  transpose_cvt_kernel<<<dim3(FD / 64, HD / 64, NE), 256, 0, stream>>>(w_down, wdb, FD, HD);

  // expert GEMMs
  up_gate_bf16<<<dim3(CAPE / 128, FD / 128, NE), 256, 0, stream>>>(xb, wub, wgb, tidx, counts, sgb, act);
  down_bf16<<<dim3(CAPE / 128, HD / 128, NE), 256, 0, stream>>>(act, wdb, tidx, tw, counts, outF);
}